// Round 1
// baseline (776.556 us; speedup 1.0000x reference)
//
#include <hip/hip_runtime.h>

#define SEQ_LEN 300
#define ROW_STRIDE 302  // 300 rates + market_price + bid
#define CHUNK 5         // elements per lane; 64*5 = 320 >= 301 cp1 slots

// One 64-lane wave per row. Lane l owns rates[5l .. 5l+5), loads only
// indices < kmax = max(bid, mp+1) (rest never needed -> skip HBM fetch),
// computes within-chunk prefix products, then a wave-level exclusive
// product scan over chunk totals. cp1[k] = base[k/5] * pref[k%5].
__global__ __launch_bounds__(256) void bidprefix_kernel(
    const float* __restrict__ in, float* __restrict__ out, int batch) {
  const int lane = threadIdx.x & 63;
  const int wave = threadIdx.x >> 6;
  const int row = blockIdx.x * 4 + wave;
  if (row >= batch) return;

  const float* __restrict__ rp = in + (long long)row * ROW_STRIDE;

  // Row-scalar indices (broadcast load, same address all lanes).
  const int mp  = (int)rp[SEQ_LEN];       // in [0, 299]
  const int bid = (int)rp[SEQ_LEN + 1];   // in [0, 300]
  const int kmax = max(bid, mp + 1);      // <= 300; cp1 never queried past it

  const int b = lane * CHUNK;
  // Predicated loads: lanes/elements past kmax contribute identity (1.0f)
  // and their cache lines are never fetched.
  float e0 = (b + 0 < kmax) ? rp[b + 0] : 1.0f;
  float e1 = (b + 1 < kmax) ? rp[b + 1] : 1.0f;
  float e2 = (b + 2 < kmax) ? rp[b + 2] : 1.0f;
  float e3 = (b + 3 < kmax) ? rp[b + 3] : 1.0f;
  float e4 = (b + 4 < kmax) ? rp[b + 4] : 1.0f;

  // Within-chunk prefix products: pref[j] = prod of first j elements.
  const float p1 = e0;
  const float p2 = p1 * e1;
  const float p3 = p2 * e2;
  const float p4 = p3 * e3;
  const float tot = p4 * e4;

  // Inclusive product scan across the wave (6 shuffle steps).
  float incl = tot;
#pragma unroll
  for (int d = 1; d < 64; d <<= 1) {
    float up = __shfl_up(incl, d, 64);
    if (lane >= d) incl *= up;
  }
  // Exclusive base: product of all chunks before this lane.
  float base = __shfl_up(incl, 1, 64);
  if (lane == 0) base = 1.0f;

  // cp1[k] lookup; k is wave-uniform (per-row scalar), k in [0, 300].
  auto lookup = [&](int k) -> float {
    const int l = k / CHUNK;          // owner lane (uniform)
    const int j = k - l * CHUNK;      // position within chunk (uniform)
    const float pj = (j == 0) ? 1.0f
                   : (j == 1) ? p1
                   : (j == 2) ? p2
                   : (j == 3) ? p3
                              : p4;
    return __shfl(base * pj, l, 64);
  };

  const float surv = lookup(bid);
  const float cpm  = lookup(mp);
  const float cpm1 = lookup(mp + 1);

  if (lane == 0) {
    out[row]         = surv;         // survival_rate
    out[batch + row] = cpm - cpm1;   // rate_last = cp1[mp] - cp1[mp+1]
  }
}

extern "C" void kernel_launch(void* const* d_in, const int* in_sizes, int n_in,
                              void* d_out, int out_size, void* d_ws, size_t ws_size,
                              hipStream_t stream) {
  (void)n_in; (void)d_ws; (void)ws_size;
  const float* in = (const float*)d_in[0];
  float* out = (float*)d_out;
  const int batch = in_sizes[0] / ROW_STRIDE;   // 500000
  const int waves_per_block = 4;                // 256 threads
  const int grid = (batch + waves_per_block - 1) / waves_per_block;
  bidprefix_kernel<<<grid, 256, 0, stream>>>(in, out, batch);
}

// Round 2
// 769.156 us; speedup vs baseline: 1.0096x; 1.0096x over previous
//
#include <hip/hip_runtime.h>

#define SEQ_LEN 300
#define ROW_STRIDE 302  // 300 rates + market_price + bid

// One 64-lane wave per row, fully coalesced interleaved layout:
//   slot s (0..2), lane l owns positions 128s + 2l and 128s + 2l + 1.
// We never need the full cumprod scan -- only cp1[] at three wave-uniform
// indices. Each lane forms two predicated partial products (idx < bid and
// idx < mp), then two independent 6-step butterfly product-reductions give
//   survival = cp1[bid], cpm = cp1[mp];  rate_last = cpm * (1 - rates[mp]).
// All rate loads are unconditional (no dependency on the index load), so
// the wave's HBM requests all issue back-to-back.
__global__ __launch_bounds__(256) void bidprefix_kernel(
    const float* __restrict__ in, float* __restrict__ out, int batch) {
  const int lane = threadIdx.x & 63;
  const int wave = threadIdx.x >> 6;
  const int row = blockIdx.x * 4 + wave;
  if (row >= batch) return;

  const float* __restrict__ rp = in + (long long)row * ROW_STRIDE;

  // Broadcast index pair (positions 300,301). Row base is 8B-aligned
  // (1208 = 151*8), so all float2 accesses below are aligned.
  const float2 idxpair = *(const float2*)(rp + SEQ_LEN);

  // Coalesced rate loads (512 B per instruction across the wave).
  const float2 v0 = *(const float2*)(rp + 2 * lane);
  const float2 v1 = *(const float2*)(rp + 128 + 2 * lane);
  float2 v2 = make_float2(1.0f, 1.0f);
  if (lane < 22) v2 = *(const float2*)(rp + 256 + 2 * lane);  // pos 256..299

  const int mp  = (int)idxpair.x;   // [0, 299]
  const int bid = (int)idxpair.y;   // [0, 300]

  // rates[mp]: broadcast re-read; the line is already in L1/L2.
  const float rmp = rp[mp];

  // element idx = 128s + 2l + c ; predicate (idx < k) <=> (2l < k - 128s - c)
  const int l2 = 2 * lane;
  float pb = 1.0f, pm = 1.0f;
  float e;
  e = (l2 < bid      ) ? v0.x : 1.0f;  pb *= e;
  e = (l2 < bid - 1  ) ? v0.y : 1.0f;  pb *= e;
  e = (l2 < bid - 128) ? v1.x : 1.0f;  pb *= e;
  e = (l2 < bid - 129) ? v1.y : 1.0f;  pb *= e;
  e = (l2 < bid - 256) ? v2.x : 1.0f;  pb *= e;
  e = (l2 < bid - 257) ? v2.y : 1.0f;  pb *= e;

  e = (l2 < mp       ) ? v0.x : 1.0f;  pm *= e;
  e = (l2 < mp - 1   ) ? v0.y : 1.0f;  pm *= e;
  e = (l2 < mp - 128 ) ? v1.x : 1.0f;  pm *= e;
  e = (l2 < mp - 129 ) ? v1.y : 1.0f;  pm *= e;
  e = (l2 < mp - 256 ) ? v2.x : 1.0f;  pm *= e;
  e = (l2 < mp - 257 ) ? v2.y : 1.0f;  pm *= e;

  // Two independent butterfly product-reductions (2-way ILP, 12 shuffles).
#pragma unroll
  for (int d = 1; d < 64; d <<= 1) {
    pb *= __shfl_xor(pb, d, 64);
    pm *= __shfl_xor(pm, d, 64);
  }

  if (lane == 0) {
    out[row]         = pb;                   // survival_rate = cp1[bid]
    out[batch + row] = pm * (1.0f - rmp);    // cp1[mp] - cp1[mp+1]
  }
}

extern "C" void kernel_launch(void* const* d_in, const int* in_sizes, int n_in,
                              void* d_out, int out_size, void* d_ws, size_t ws_size,
                              hipStream_t stream) {
  (void)n_in; (void)d_ws; (void)ws_size; (void)out_size;
  const float* in = (const float*)d_in[0];
  float* out = (float*)d_out;
  const int batch = in_sizes[0] / ROW_STRIDE;   // 500000
  const int waves_per_block = 4;                // 256 threads
  const int grid = (batch + waves_per_block - 1) / waves_per_block;
  bidprefix_kernel<<<grid, 256, 0, stream>>>(in, out, batch);
}